// Round 9
// baseline (275.904 us; speedup 1.0000x reference)
//
#include <hip/hip_runtime.h>
#include <math.h>

#define HH 256
#define NN 64
#define LL 4096
#define BB 8
#define CC 4            // L-chunks (= waves per scan block); 8192 waves = 1 full round
#define LC (LL / CC)    // 1024
#define GG 16           // blocked-Horner group size
#define HN (HH * NN)    // 16384

typedef __attribute__((ext_vector_type(2))) float pf2;
typedef __attribute__((ext_vector_type(16))) float f16v;
typedef const __attribute__((address_space(4))) f16v* cf16p;  // -> s_load_dwordx16

// ws layout (floats):
//   dA   (float2[HN])          @ 0         (32768 floats)
//   wv   (float2[HN])          @ 32768     (32768)
//   pw   (float2[CC][HN])      @ 65536     (131072)
//   u_ws (float [B][H][L])     @ 327680    (8388608)
//   g    (float [B][H])        @ 10813440  (2048)
//   cnt  (int [B])             @ 10815488  (8)

// Fused frontend: blocks [0,512) materialize u (gather+transpose);
// blocks [512,576) do the per-(h,n) constant precompute + zero counters.
__global__ __launch_bounds__(256) void frontend_kernel(
    const int* __restrict__ ids, const float* __restrict__ emb,
    const float* __restrict__ log_dt, const float* __restrict__ A_log_re,
    const float* __restrict__ A_im, const float* __restrict__ B_re,
    const float* __restrict__ B_im, const float* __restrict__ C_re,
    const float* __restrict__ C_im,
    float2* __restrict__ dAo, float2* __restrict__ wo, float2* __restrict__ pw,
    float* __restrict__ u_ws, int* __restrict__ cnt) {
    __shared__ int ids_s[64];
    __shared__ float tb[64][257];   // [s][h], odd stride: transpose reads free
    int t = threadIdx.x;
    if (blockIdx.x < BB * 64) {
        // ---- gather: u[b][h][s] = emb[ids[b][s]][h], coalesced both ways ----
        int b = blockIdx.x >> 6;
        int tile = blockIdx.x & 63;
        int w4 = t >> 6, lane = t & 63;
        if (t < 64) ids_s[t] = ids[b * LL + tile * 64 + t];
        __syncthreads();
        #pragma unroll 4
        for (int r = w4; r < 64; r += 4) {
            float4 v = ((const float4*)(emb + (long)ids_s[r] * HH))[lane];
            tb[r][lane * 4 + 0] = v.x;
            tb[r][lane * 4 + 1] = v.y;
            tb[r][lane * 4 + 2] = v.z;
            tb[r][lane * 4 + 3] = v.w;
        }
        __syncthreads();
        #pragma unroll 4
        for (int r2 = 0; r2 < 64; ++r2) {
            int h = w4 * 64 + r2;
            u_ws[(b * HH + h) * LL + tile * 64 + lane] = tb[lane][h];
        }
    } else {
        // ---- precompute: dA, w = 2*C0*dB, pw[k] = dA^(1024k); zero cnt ----
        if (blockIdx.x == BB * 64 && t < BB) cnt[t] = 0;
        int idx = (blockIdx.x - BB * 64) * 256 + t;   // h*64+n
        int h = idx >> 6;
        float dt = expf(log_dt[h]);
        float Are = -expf(A_log_re[idx]);
        float Aim = A_im[idx];
        float ea = expf(dt * Are);
        float sn, cs;
        sincosf(dt * Aim, &sn, &cs);
        float dAre = ea * cs, dAim = ea * sn;
        float numre = dAre - 1.0f, numim = dAim;
        float den = Are * Are + Aim * Aim;
        float qre = (numre * Are + numim * Aim) / den;
        float qim = (numim * Are - numre * Aim) / den;
        float bre = B_re[idx], bim = B_im[idx];
        float dBre = bre * qre - bim * qim;
        float dBim = bre * qim + bim * qre;
        float cre = C_re[idx], cim = C_im[idx];
        dAo[idx] = make_float2(dAre, dAim);
        wo[idx] = make_float2(2.0f * (cre * dBre - cim * dBim),
                              2.0f * (cre * dBim + cim * dBre));
        float pr = dAre, pi = dAim;
        #pragma unroll
        for (int k = 0; k < 10; ++k) {       // dA^1024
            float nr = pr * pr - pi * pi;
            float ni = 2.0f * pr * pi;
            pr = nr; pi = ni;
        }
        float qr = 1.0f, qi = 0.0f;
        #pragma unroll
        for (int k = 0; k < CC; ++k) {       // pw[k] = dA^(1024k)
            pw[k * HN + idx] = make_float2(qr, qi);
            float nr = qr * pr - qi * pi, ni = qr * pi + qi * pr;
            qr = nr; qi = ni;
        }
    }
}

// Fused scan+combine+epilogue: one block per (b,h), 4 waves = 4 L-chunks.
// Blocked-Horner, s_load_dwordx16 u-loads, v_pk_fma_f32. Wave 0 reduces,
// projects through wv, GELU -> g[bh], then last-block-per-b idiom runs the
// W_out projection + GLU for that b (overlapped with remaining scan blocks).
// grid = B*H = 2048 blocks, block = 256 (8 blocks/CU = 32 waves/CU).
__global__ __launch_bounds__(256) void scan_kernel(
    const float* __restrict__ u_ws, const float2* __restrict__ dAv,
    const float2* __restrict__ pw, const float2* __restrict__ wv,
    const float* __restrict__ D, float* __restrict__ g,
    int* __restrict__ cnt, const float* __restrict__ W,
    const float* __restrict__ bvec, float* __restrict__ out) {
    __shared__ float2 part[CC][NN];   // 2 KB
    __shared__ float gbuf[HH];
    __shared__ float zbuf[2 * HH];
    __shared__ int winflag;
    int t = threadIdx.x;
    int c = __builtin_amdgcn_readfirstlane(t >> 6);   // wave id = chunk
    int n = t & 63;
    int bh = blockIdx.x;
    int h = bh & (HH - 1);
    int b = bh >> 8;

    float2 dA = dAv[h * NN + n];
    // Q[k] = dA^(GG-1-k) as (re,im) pairs; R = dA^GG
    pf2 Q[GG];
    pf2 q; q.x = 1.0f; q.y = 0.0f;
    #pragma unroll
    for (int k = 0; k < GG; ++k) {
        Q[GG - 1 - k] = q;
        pf2 nq;
        nq.x = q.x * dA.x - q.y * dA.y;
        nq.y = q.x * dA.y + q.y * dA.x;
        q = nq;
    }
    pf2 Rp; Rp.x = q.x; Rp.y = q.x;      // (Rr, Rr)
    pf2 Rm; Rm.x = -q.y; Rm.y = q.y;     // (-Ri, Ri)

    cf16p src = (cf16p)(unsigned long long)(u_ws + bh * LL + c * LC);
    pf2 P; P.x = 0.0f; P.y = 0.0f;
    #pragma unroll 4
    for (int j = 0; j < LC / GG; ++j) {  // 64 groups of 16
        f16v u = src[j];                 // one s_load_dwordx16 (64 B line)
        pf2 T; T.x = 0.0f; T.y = 0.0f;
        #pragma unroll
        for (int k = 0; k < GG; ++k) {
            pf2 ub; ub.x = u[k]; ub.y = u[k];
            T = __builtin_elementwise_fma(ub, Q[k], T);   // v_pk_fma_f32
        }
        // P = P*R + T (complex): 2 pk_fma + swap
        pf2 Ps; Ps.x = P.y; Ps.y = P.x;
        P = __builtin_elementwise_fma(P, Rp, __builtin_elementwise_fma(Ps, Rm, T));
    }
    // scale by dA^(1024*(CC-1-c)) and stash in LDS
    float2 sc = pw[(CC - 1 - c) * HN + h * NN + n];
    part[c][n] = make_float2(P.x * sc.x - P.y * sc.y,
                             P.x * sc.y + P.y * sc.x);
    __syncthreads();

    if (c == 0) {
        float Sr = 0.0f, Si = 0.0f;
        #pragma unroll
        for (int cc2 = 0; cc2 < CC; ++cc2) {
            float2 v = part[cc2][n];
            Sr += v.x; Si += v.y;
        }
        float2 wc = wv[h * NN + n];
        float contrib = fmaf(wc.x, Sr, -(wc.y * Si));
        #pragma unroll
        for (int m = 32; m > 0; m >>= 1) contrib += __shfl_xor(contrib, m);
        if (n == 0) {
            float y = contrib + u_ws[bh * LL + LL - 1] * D[h];
            float ge = 0.5f * y * (1.0f + erff(y * 0.70710678118654752f));
            g[bh] = ge;
            __threadfence();                      // publish g before counting
            int old = atomicAdd(&cnt[b], 1);      // device-scope
            __threadfence();                      // acquire for winner's reads
            winflag = (old == HH - 1) ? 1 : 0;
        }
    }
    __syncthreads();   // broadcasts winflag; orders after lane0's fences

    if (winflag) {
        // ---- last block for this b: W_out projection + GLU ----
        gbuf[t] = g[b * HH + t];
        __syncthreads();
        const float4* W4 = (const float4*)W;
        const float4* g4p = (const float4*)gbuf;
        float4 gv4 = g4p[n];
        #pragma unroll 4
        for (int r = 0; r < 128; ++r) {
            int o = c * 128 + r;                  // wave c covers 128 rows
            float4 w4 = W4[o * 64 + n];
            float p = w4.x * gv4.x + w4.y * gv4.y + w4.z * gv4.z + w4.w * gv4.w;
            #pragma unroll
            for (int m = 32; m > 0; m >>= 1) p += __shfl_xor(p, m);
            if (n == 0) zbuf[o] = p + bvec[o];
        }
        __syncthreads();
        float z1 = zbuf[t];
        float z2 = zbuf[t + HH];
        out[b * HH + t] = z1 * (1.0f / (1.0f + expf(-z2)));
    }
}

extern "C" void kernel_launch(void* const* d_in, const int* in_sizes, int n_in,
                              void* d_out, int out_size, void* d_ws, size_t ws_size,
                              hipStream_t stream) {
    const int* input_ids = (const int*)d_in[0];
    const float* embedding = (const float*)d_in[1];
    const float* log_dt = (const float*)d_in[2];
    const float* A_log_re = (const float*)d_in[3];
    const float* A_im = (const float*)d_in[4];
    const float* B_re = (const float*)d_in[5];
    const float* B_im = (const float*)d_in[6];
    const float* C_re = (const float*)d_in[7];
    const float* C_im = (const float*)d_in[8];
    const float* D = (const float*)d_in[9];
    const float* W_out = (const float*)d_in[10];
    const float* b_out = (const float*)d_in[11];
    float* out = (float*)d_out;

    float* ws = (float*)d_ws;
    float2* dAv = (float2*)ws;                    // HN float2
    float2* wv = (float2*)(ws + 32768);           // HN float2
    float2* pw = (float2*)(ws + 65536);           // CC*HN float2
    float* u_ws = ws + 327680;                    // B*H*L floats
    float* g = ws + 10813440;                     // B*H floats
    int* cnt = (int*)(ws + 10815488);             // B ints

    frontend_kernel<<<BB * 64 + HN / 256, 256, 0, stream>>>(
        input_ids, embedding, log_dt, A_log_re, A_im, B_re, B_im, C_re, C_im,
        dAv, wv, pw, u_ws, cnt);

    scan_kernel<<<BB * HH, 256, 0, stream>>>(
        u_ws, dAv, pw, wv, D, g, cnt, W_out, b_out, out);
}

// Round 10
// 132.565 us; speedup vs baseline: 2.0813x; 2.0813x over previous
//
#include <hip/hip_runtime.h>
#include <math.h>

#define HH 256
#define NN 64
#define LL 4096
#define BB 8
#define CC 8            // L-chunks for parallelism (= waves per scan block)
#define LC (LL / CC)    // 512
#define GG 16           // blocked-Horner group size
#define HN (HH * NN)    // 16384

typedef __attribute__((ext_vector_type(2))) float pf2;
typedef __attribute__((ext_vector_type(16))) float f16v;
typedef const __attribute__((address_space(4))) f16v* cf16p;  // -> s_load_dwordx16

// ws layout (floats):
//   dA   (float2[HN])          @ 0         (32768 floats)
//   wv   (float2[HN])          @ 32768     (32768)
//   pw   (float2[CC][HN])      @ 65536     (262144)
//   u_ws (float [B][H][L])     @ 327680    (8388608)
//   g    (float [B][H])        @ 10813440  (2048)

// Fused frontend: blocks [0,512) materialize u (gather+transpose);
// blocks [512,576) do the per-(h,n) constant precompute. Independent work,
// one dispatch, concurrent execution.
__global__ __launch_bounds__(256) void frontend_kernel(
    const int* __restrict__ ids, const float* __restrict__ emb,
    const float* __restrict__ log_dt, const float* __restrict__ A_log_re,
    const float* __restrict__ A_im, const float* __restrict__ B_re,
    const float* __restrict__ B_im, const float* __restrict__ C_re,
    const float* __restrict__ C_im,
    float2* __restrict__ dAo, float2* __restrict__ wo, float2* __restrict__ pw,
    float* __restrict__ u_ws) {
    __shared__ int ids_s[64];
    __shared__ float tb[64][257];   // [s][h], odd stride: transpose reads free
    int t = threadIdx.x;
    if (blockIdx.x < BB * 64) {
        // ---- gather: u[b][h][s] = emb[ids[b][s]][h], coalesced both ways ----
        int b = blockIdx.x >> 6;
        int tile = blockIdx.x & 63;
        int w4 = t >> 6, lane = t & 63;
        if (t < 64) ids_s[t] = ids[b * LL + tile * 64 + t];
        __syncthreads();
        #pragma unroll 4
        for (int r = w4; r < 64; r += 4) {
            float4 v = ((const float4*)(emb + (long)ids_s[r] * HH))[lane];
            tb[r][lane * 4 + 0] = v.x;
            tb[r][lane * 4 + 1] = v.y;
            tb[r][lane * 4 + 2] = v.z;
            tb[r][lane * 4 + 3] = v.w;
        }
        __syncthreads();
        #pragma unroll 4
        for (int r2 = 0; r2 < 64; ++r2) {
            int h = w4 * 64 + r2;
            u_ws[(b * HH + h) * LL + tile * 64 + lane] = tb[lane][h];
        }
    } else {
        // ---- precompute: dA, w = 2*C0*dB, pw[k] = dA^(512k) ----
        int idx = (blockIdx.x - BB * 64) * 256 + t;   // h*64+n
        int h = idx >> 6;
        float dt = expf(log_dt[h]);
        float Are = -expf(A_log_re[idx]);
        float Aim = A_im[idx];
        float ea = expf(dt * Are);
        float sn, cs;
        sincosf(dt * Aim, &sn, &cs);
        float dAre = ea * cs, dAim = ea * sn;
        float numre = dAre - 1.0f, numim = dAim;
        float den = Are * Are + Aim * Aim;
        float qre = (numre * Are + numim * Aim) / den;
        float qim = (numim * Are - numre * Aim) / den;
        float bre = B_re[idx], bim = B_im[idx];
        float dBre = bre * qre - bim * qim;
        float dBim = bre * qim + bim * qre;
        float cre = C_re[idx], cim = C_im[idx];
        dAo[idx] = make_float2(dAre, dAim);
        wo[idx] = make_float2(2.0f * (cre * dBre - cim * dBim),
                              2.0f * (cre * dBim + cim * dBre));
        float pr = dAre, pi = dAim;
        #pragma unroll
        for (int k = 0; k < 9; ++k) {        // dA^512
            float nr = pr * pr - pi * pi;
            float ni = 2.0f * pr * pi;
            pr = nr; pi = ni;
        }
        float qr = 1.0f, qi = 0.0f;
        #pragma unroll
        for (int k = 0; k < CC; ++k) {
            pw[k * HN + idx] = make_float2(qr, qi);
            float nr = qr * pr - qi * pi, ni = qr * pi + qi * pr;
            qr = nr; qi = ni;
        }
    }
}

// Fused scan+combine: one block per (b,h), 8 waves = 8 L-chunks. Each wave:
// blocked-Horner with s_load_dwordx16 u-loads + v_pk_fma_f32, scales its
// partial by pw[7-c] in-register, drops it in LDS; wave 0 reduces, projects
// through wv, adds D-term, GELU, writes g. No p_ws global round-trip.
// grid = B*H = 2048 blocks, block = 512.
__global__ __launch_bounds__(512) void scan_kernel(
    const float* __restrict__ u_ws, const float2* __restrict__ dAv,
    const float2* __restrict__ pw, const float2* __restrict__ wv,
    const float* __restrict__ D, float* __restrict__ g) {
    __shared__ float2 part[CC][NN];   // 4 KB
    int t = threadIdx.x;
    int c = __builtin_amdgcn_readfirstlane(t >> 6);   // wave id = chunk
    int n = t & 63;
    int bh = blockIdx.x;
    int h = bh & (HH - 1);

    float2 dA = dAv[h * NN + n];
    // Q[k] = dA^(GG-1-k) as (re,im) pairs; R = dA^GG
    pf2 Q[GG];
    pf2 q; q.x = 1.0f; q.y = 0.0f;
    #pragma unroll
    for (int k = 0; k < GG; ++k) {
        Q[GG - 1 - k] = q;
        pf2 nq;
        nq.x = q.x * dA.x - q.y * dA.y;
        nq.y = q.x * dA.y + q.y * dA.x;
        q = nq;
    }
    pf2 Rp; Rp.x = q.x; Rp.y = q.x;      // (Rr, Rr)
    pf2 Rm; Rm.x = -q.y; Rm.y = q.y;     // (-Ri, Ri)

    cf16p src = (cf16p)(unsigned long long)(u_ws + bh * LL + c * LC);
    pf2 P; P.x = 0.0f; P.y = 0.0f;
    #pragma unroll 4
    for (int j = 0; j < LC / GG; ++j) {  // 32 groups of 16
        f16v u = src[j];                 // one s_load_dwordx16
        pf2 T; T.x = 0.0f; T.y = 0.0f;
        #pragma unroll
        for (int k = 0; k < GG; ++k) {
            pf2 ub; ub.x = u[k]; ub.y = u[k];
            T = __builtin_elementwise_fma(ub, Q[k], T);   // v_pk_fma_f32
        }
        // P = P*R + T (complex): 2 pk_fma + swap
        pf2 Ps; Ps.x = P.y; Ps.y = P.x;
        P = __builtin_elementwise_fma(P, Rp, __builtin_elementwise_fma(Ps, Rm, T));
    }
    // scale by dA^(512*(CC-1-c)) and stash in LDS
    float2 sc = pw[(CC - 1 - c) * HN + h * NN + n];
    part[c][n] = make_float2(P.x * sc.x - P.y * sc.y,
                             P.x * sc.y + P.y * sc.x);
    __syncthreads();

    if (c == 0) {
        float Sr = 0.0f, Si = 0.0f;
        #pragma unroll
        for (int cc = 0; cc < CC; ++cc) {
            float2 v = part[cc][n];
            Sr += v.x; Si += v.y;
        }
        float2 wc = wv[h * NN + n];
        float contrib = fmaf(wc.x, Sr, -(wc.y * Si));
        #pragma unroll
        for (int m = 32; m > 0; m >>= 1) contrib += __shfl_xor(contrib, m);
        if (n == 0) {
            float y = contrib + u_ws[bh * LL + LL - 1] * D[h];
            float ge = 0.5f * y * (1.0f + erff(y * 0.70710678118654752f));
            g[bh] = ge;
        }
    }
}

// Output projection + GLU. grid = B*128 (2 h per block), block = 256 (4 waves).
__global__ __launch_bounds__(256) void out_kernel(
    const float* __restrict__ g, const float* __restrict__ W,
    const float* __restrict__ bvec, float* __restrict__ out) {
    int b = blockIdx.x >> 7;
    int tile = blockIdx.x & 127;
    int t = threadIdx.x;
    int w = t >> 6, lane = t & 63;
    __shared__ float gs[HH];
    __shared__ float zb[4];
    gs[t] = g[b * HH + t];
    __syncthreads();
    int hh = tile * 2 + (w >> 1);
    int o = (w & 1) * HH + hh;
    float4 wv4 = ((const float4*)(W + o * HH))[lane];
    float4 gv4 = ((const float4*)gs)[lane];
    float p = wv4.x * gv4.x + wv4.y * gv4.y + wv4.z * gv4.z + wv4.w * gv4.w;
    #pragma unroll
    for (int m = 32; m > 0; m >>= 1) p += __shfl_xor(p, m);
    if (lane == 0) zb[w] = p + bvec[o];
    __syncthreads();
    if (t < 2) {
        int hq = tile * 2 + t;
        float z1 = zb[t * 2 + 0];
        float z2 = zb[t * 2 + 1];
        out[b * HH + hq] = z1 * (1.0f / (1.0f + expf(-z2)));
    }
}

extern "C" void kernel_launch(void* const* d_in, const int* in_sizes, int n_in,
                              void* d_out, int out_size, void* d_ws, size_t ws_size,
                              hipStream_t stream) {
    const int* input_ids = (const int*)d_in[0];
    const float* embedding = (const float*)d_in[1];
    const float* log_dt = (const float*)d_in[2];
    const float* A_log_re = (const float*)d_in[3];
    const float* A_im = (const float*)d_in[4];
    const float* B_re = (const float*)d_in[5];
    const float* B_im = (const float*)d_in[6];
    const float* C_re = (const float*)d_in[7];
    const float* C_im = (const float*)d_in[8];
    const float* D = (const float*)d_in[9];
    const float* W_out = (const float*)d_in[10];
    const float* b_out = (const float*)d_in[11];
    float* out = (float*)d_out;

    float* ws = (float*)d_ws;
    float2* dAv = (float2*)ws;                    // HN float2
    float2* wv = (float2*)(ws + 32768);           // HN float2
    float2* pw = (float2*)(ws + 65536);           // CC*HN float2
    float* u_ws = ws + 327680;                    // B*H*L floats
    float* g = ws + 10813440;                     // B*H floats

    frontend_kernel<<<BB * 64 + HN / 256, 256, 0, stream>>>(
        input_ids, embedding, log_dt, A_log_re, A_im, B_re, B_im, C_re, C_im,
        dAv, wv, pw, u_ws);

    scan_kernel<<<BB * HH, 512, 0, stream>>>(u_ws, dAv, pw, wv, D, g);

    out_kernel<<<BB * 128, 256, 0, stream>>>(g, W_out, b_out, out);
}